// Round 1
// baseline (1020.671 us; speedup 1.0000x reference)
//
#include <hip/hip_runtime.h>
#include <cstdint>
#include <cstddef>

#define B_SZ 2
#define SEQL 2048
#define DMODEL 1024
#define NSTATE 16
#define M_TOTAL (B_SZ * SEQL)      // 4096 rows of x
#define NW_REAL 1056               // Wdelta(1024) + Wb(16) + Wc(16)
#define NW_ALL  1152               // padded to 9 x 128 tiles
#define XN (M_TOTAL * DMODEL)      // 4,194,304
#define WN (NW_ALL * DMODEL)       // 1,179,648

typedef unsigned short ushort_t;

// ---------- fp32 -> bf16 (RNE) ----------
__device__ __forceinline__ ushort_t f2bf(float f) {
    unsigned int u = __float_as_uint(f);
    u = (u + 0x7FFFu + ((u >> 16) & 1u)) >> 16;
    return (ushort_t)u;
}

// Converts x (4096x1024) and the concatenated weight matrix
// [Wdelta; Wb; Wc; zero-pad] (1152x1024) to bf16 in workspace.
__global__ __launch_bounds__(256) void convert_kernel(
    const float* __restrict__ x, const float* __restrict__ Wd,
    const float* __restrict__ Wb, const float* __restrict__ Wc,
    ushort_t* __restrict__ x16, ushort_t* __restrict__ w16) {
    int t = blockIdx.x * 256 + threadIdx.x;
    int i = t * 4;
    if (i < XN) {
        float4 v = *(const float4*)(x + i);
        ushort4 o;
        o.x = f2bf(v.x); o.y = f2bf(v.y); o.z = f2bf(v.z); o.w = f2bf(v.w);
        *(ushort4*)(x16 + i) = o;
    } else {
        int j = i - XN;                 // 0 .. WN-1
        int row = j >> 10, col = j & 1023;
        float4 v;
        if (row < 1024)      v = *(const float4*)(Wd + row * 1024 + col);
        else if (row < 1040) v = *(const float4*)(Wb + (row - 1024) * 1024 + col);
        else if (row < 1056) v = *(const float4*)(Wc + (row - 1040) * 1024 + col);
        else                 v = make_float4(0.f, 0.f, 0.f, 0.f);
        ushort4 o;
        o.x = f2bf(v.x); o.y = f2bf(v.y); o.z = f2bf(v.z); o.w = f2bf(v.w);
        *(ushort4*)(w16 + j) = o;
    }
}

// ---------- MFMA GEMM: out = x16 @ w16^T, fused epilogue ----------
typedef __attribute__((ext_vector_type(8))) short frag_ab;
typedef __attribute__((ext_vector_type(4))) float frag_cd;

__device__ __forceinline__ void lds_load16(const ushort_t* g, ushort_t* l) {
    __builtin_amdgcn_global_load_lds(
        (const __attribute__((address_space(1))) unsigned int*)g,
        (__attribute__((address_space(3))) unsigned int*)l, 16, 0, 0);
}

// 128x128 tile, BK=32, 4 waves (2x2), each wave 64x64 via 4x4 MFMAs of 16x16x32.
// grid = (32, 9): M tiles x N tiles (last N tile only cols 1024..1055 valid).
__global__ __launch_bounds__(256) void gemm_kernel(
    const ushort_t* __restrict__ x16, const ushort_t* __restrict__ w16,
    const float* __restrict__ bdelta,
    float* __restrict__ delta, float* __restrict__ Bmb, float* __restrict__ Cmb) {
    __shared__ ushort_t sA[128 * 32];
    __shared__ ushort_t sB[128 * 32];
    const int tid = threadIdx.x;
    const int lane = tid & 63;
    const int wv = tid >> 6;
    const int wy = wv >> 1, wx = wv & 1;
    const int m15 = lane & 15, kq = lane >> 4;   // kq in 0..3
    const int rowA0 = blockIdx.x * 128;
    const int rowB0 = blockIdx.y * 128;

    frag_cd acc[4][4];
#pragma unroll
    for (int i = 0; i < 4; i++)
#pragma unroll
        for (int j = 0; j < 4; j++)
            acc[i][j] = (frag_cd){0.f, 0.f, 0.f, 0.f};

    // staging map: chunk c (0..511) -> tile row c/4, col8 (c&3)*8, lds elem c*8
    const int c0 = tid, c1 = tid + 256;
    const int rA0 = c0 >> 2, cA0 = (c0 & 3) * 8;
    const int rA1 = c1 >> 2, cA1 = (c1 & 3) * 8;

    for (int k0 = 0; k0 < 1024; k0 += 32) {
        __syncthreads();
        lds_load16(x16 + (size_t)(rowA0 + rA0) * 1024 + k0 + cA0, sA + c0 * 8);
        lds_load16(x16 + (size_t)(rowA0 + rA1) * 1024 + k0 + cA1, sA + c1 * 8);
        lds_load16(w16 + (size_t)(rowB0 + rA0) * 1024 + k0 + cA0, sB + c0 * 8);
        lds_load16(w16 + (size_t)(rowB0 + rA1) * 1024 + k0 + cA1, sB + c1 * 8);
        __syncthreads();   // includes vmcnt(0) drain of global_load_lds

        frag_ab af[4], bfr[4];
#pragma unroll
        for (int i = 0; i < 4; i++)
            af[i] = *(const frag_ab*)(sA + ((wy * 64 + i * 16 + m15) * 32 + kq * 8));
#pragma unroll
        for (int j = 0; j < 4; j++)
            bfr[j] = *(const frag_ab*)(sB + ((wx * 64 + j * 16 + m15) * 32 + kq * 8));
#pragma unroll
        for (int i = 0; i < 4; i++)
#pragma unroll
            for (int j = 0; j < 4; j++)
                acc[i][j] = __builtin_amdgcn_mfma_f32_16x16x32_bf16(
                    af[i], bfr[j], acc[i][j], 0, 0, 0);
    }

    // Epilogue: D elem (reg r): row = m-base + kq*4 + r, col = n-base + m15
#pragma unroll
    for (int j = 0; j < 4; j++) {
        int col = rowB0 + wx * 64 + j * 16 + m15;
        if (col >= NW_REAL) continue;
        if (col < 1024) {
            float bd = bdelta[col];
#pragma unroll
            for (int i = 0; i < 4; i++) {
#pragma unroll
                for (int r = 0; r < 4; r++) {
                    int row = rowA0 + wy * 64 + i * 16 + kq * 4 + r;
                    float z = acc[i][j][r] + bd;
                    float sp = (z > 20.f) ? z : log1pf(__expf(z));
                    delta[(size_t)row * 1024 + col] = sp;
                }
            }
        } else if (col < 1040) {
            int c = col - 1024;
#pragma unroll
            for (int i = 0; i < 4; i++)
#pragma unroll
                for (int r = 0; r < 4; r++) {
                    int row = rowA0 + wy * 64 + i * 16 + kq * 4 + r;
                    Bmb[(size_t)row * 16 + c] = acc[i][j][r];
                }
        } else {
            int c = col - 1040;
#pragma unroll
            for (int i = 0; i < 4; i++)
#pragma unroll
                for (int r = 0; r < 4; r++) {
                    int row = rowA0 + wy * 64 + i * 16 + kq * 4 + r;
                    Cmb[(size_t)row * 16 + c] = acc[i][j][r];
                }
        }
    }
}

// ---------- sequential scan: thread = (b, d, n), shuffle-reduce over n ----------
__global__ __launch_bounds__(256) void scan_kernel(
    const float* __restrict__ delta, const float* __restrict__ Bmb,
    const float* __restrict__ Cmb, const float* __restrict__ x,
    const float* __restrict__ log_A, const float* __restrict__ Dv,
    float* __restrict__ y) {
    int gt = blockIdx.x * 256 + threadIdx.x;   // 0..32767
    int n = gt & 15;
    int d = (gt >> 4) & (DMODEL - 1);
    int b = gt >> 14;
    float A = -expf(log_A[d * NSTATE + n]);
    float Dd = Dv[d];
    float h = 0.f;
    size_t idx_dx = (size_t)b * SEQL * DMODEL + d;    // stride DMODEL per l
    size_t idx_bc = (size_t)b * SEQL * NSTATE + n;    // stride NSTATE per l
#pragma unroll 4
    for (int l = 0; l < SEQL; ++l) {
        float dl = delta[idx_dx];
        float xl = x[idx_dx];
        float bm = Bmb[idx_bc];
        float cm = Cmb[idx_bc];
        float a = __expf(dl * A);
        h = fmaf(a, h, dl * bm * xl);
        float yc = h * cm;
        yc += __shfl_xor(yc, 1);
        yc += __shfl_xor(yc, 2);
        yc += __shfl_xor(yc, 4);
        yc += __shfl_xor(yc, 8);
        if (n == 0) y[idx_dx] = fmaf(xl, Dd, yc);
        idx_dx += DMODEL;
        idx_bc += NSTATE;
    }
}

extern "C" void kernel_launch(void* const* d_in, const int* in_sizes, int n_in,
                              void* d_out, int out_size, void* d_ws, size_t ws_size,
                              hipStream_t stream) {
    const float* x      = (const float*)d_in[0];
    const float* Wb     = (const float*)d_in[1];
    const float* Wc     = (const float*)d_in[2];
    const float* Wdelta = (const float*)d_in[3];
    const float* bdelta = (const float*)d_in[4];
    const float* log_A  = (const float*)d_in[5];
    const float* Dv     = (const float*)d_in[6];
    float* y = (float*)d_out;

    char* ws = (char*)d_ws;
    ushort_t* x16 = (ushort_t*)ws;                               // 8,388,608 B
    ushort_t* w16 = (ushort_t*)(ws + 8388608);                   // 2,359,296 B
    float* delta  = (float*)(ws + 8388608 + 2359296);            // 16,777,216 B
    float* Bmb    = (float*)(ws + 8388608 + 2359296 + 16777216); //   262,144 B
    float* Cmb    = (float*)(ws + 8388608 + 2359296 + 16777216 + 262144);

    convert_kernel<<<(XN + WN) / 4 / 256, 256, 0, stream>>>(x, Wdelta, Wb, Wc, x16, w16);
    gemm_kernel<<<dim3(32, 9), 256, 0, stream>>>(x16, w16, bdelta, delta, Bmb, Cmb);
    scan_kernel<<<(B_SZ * DMODEL * NSTATE) / 256, 256, 0, stream>>>(
        delta, Bmb, Cmb, x, log_A, Dv, y);
}

// Round 3
// 265.839 us; speedup vs baseline: 3.8394x; 3.8394x over previous
//
#include <hip/hip_runtime.h>
#include <cstdint>
#include <cstddef>

#define B_SZ 2
#define SEQL 2048
#define DMODEL 1024
#define NSTATE 16
#define M_TOTAL (B_SZ * SEQL)      // 4096 rows of x
#define NW_REAL 1056               // Wdelta(1024) + Wb(16) + Wc(16)
#define NW_ALL  1152               // padded to 9 x 128 tiles
#define XN (M_TOTAL * DMODEL)      // 4,194,304
#define WN (NW_ALL * DMODEL)       // 1,179,648

typedef unsigned short ushort_t;

// ---------- fp32 -> bf16 (RNE) ----------
__device__ __forceinline__ ushort_t f2bf(float f) {
    unsigned int u = __float_as_uint(f);
    u = (u + 0x7FFFu + ((u >> 16) & 1u)) >> 16;
    return (ushort_t)u;
}

// Converts x (4096x1024) and the concatenated weight matrix
// [Wdelta; Wb; Wc; zero-pad] (1152x1024) to bf16 in workspace.
__global__ __launch_bounds__(256) void convert_kernel(
    const float* __restrict__ x, const float* __restrict__ Wd,
    const float* __restrict__ Wb, const float* __restrict__ Wc,
    ushort_t* __restrict__ x16, ushort_t* __restrict__ w16) {
    int t = blockIdx.x * 256 + threadIdx.x;
    int i = t * 4;
    if (i < XN) {
        float4 v = *(const float4*)(x + i);
        ushort4 o;
        o.x = f2bf(v.x); o.y = f2bf(v.y); o.z = f2bf(v.z); o.w = f2bf(v.w);
        *(ushort4*)(x16 + i) = o;
    } else {
        int j = i - XN;                 // 0 .. WN-1
        int row = j >> 10, col = j & 1023;
        float4 v;
        if (row < 1024)      v = *(const float4*)(Wd + row * 1024 + col);
        else if (row < 1040) v = *(const float4*)(Wb + (row - 1024) * 1024 + col);
        else if (row < 1056) v = *(const float4*)(Wc + (row - 1040) * 1024 + col);
        else                 v = make_float4(0.f, 0.f, 0.f, 0.f);
        ushort4 o;
        o.x = f2bf(v.x); o.y = f2bf(v.y); o.z = f2bf(v.z); o.w = f2bf(v.w);
        *(ushort4*)(w16 + j) = o;
    }
}

// ---------- MFMA GEMM: out = x16 @ w16^T, fused epilogue ----------
typedef __attribute__((ext_vector_type(8))) short frag_ab;
typedef __attribute__((ext_vector_type(4))) float frag_cd;

__device__ __forceinline__ void lds_load16(const ushort_t* g, ushort_t* l) {
    __builtin_amdgcn_global_load_lds(
        (const __attribute__((address_space(1))) unsigned int*)g,
        (__attribute__((address_space(3))) unsigned int*)l, 16, 0, 0);
}

// 128x128 tile, BK=32, 4 waves (2x2), each wave 64x64 via 4x4 MFMAs of 16x16x32.
// grid = (32, 9): M tiles x N tiles (last N tile only cols 1024..1055 valid).
__global__ __launch_bounds__(256) void gemm_kernel(
    const ushort_t* __restrict__ x16, const ushort_t* __restrict__ w16,
    const float* __restrict__ bdelta,
    float* __restrict__ delta, float* __restrict__ Bmb, float* __restrict__ Cmb) {
    __shared__ ushort_t sA[128 * 32];
    __shared__ ushort_t sB[128 * 32];
    const int tid = threadIdx.x;
    const int lane = tid & 63;
    const int wv = tid >> 6;
    const int wy = wv >> 1, wx = wv & 1;
    const int m15 = lane & 15, kq = lane >> 4;   // kq in 0..3
    const int rowA0 = blockIdx.x * 128;
    const int rowB0 = blockIdx.y * 128;

    frag_cd acc[4][4];
#pragma unroll
    for (int i = 0; i < 4; i++)
#pragma unroll
        for (int j = 0; j < 4; j++)
            acc[i][j] = (frag_cd){0.f, 0.f, 0.f, 0.f};

    // staging map: chunk c (0..511) -> tile row c/4, col8 (c&3)*8, lds elem c*8
    const int c0 = tid, c1 = tid + 256;
    const int rA0 = c0 >> 2, cA0 = (c0 & 3) * 8;
    const int rA1 = c1 >> 2, cA1 = (c1 & 3) * 8;

    for (int k0 = 0; k0 < 1024; k0 += 32) {
        __syncthreads();
        lds_load16(x16 + (size_t)(rowA0 + rA0) * 1024 + k0 + cA0, sA + c0 * 8);
        lds_load16(x16 + (size_t)(rowA0 + rA1) * 1024 + k0 + cA1, sA + c1 * 8);
        lds_load16(w16 + (size_t)(rowB0 + rA0) * 1024 + k0 + cA0, sB + c0 * 8);
        lds_load16(w16 + (size_t)(rowB0 + rA1) * 1024 + k0 + cA1, sB + c1 * 8);
        __syncthreads();   // includes vmcnt(0) drain of global_load_lds

        frag_ab af[4], bfr[4];
#pragma unroll
        for (int i = 0; i < 4; i++)
            af[i] = *(const frag_ab*)(sA + ((wy * 64 + i * 16 + m15) * 32 + kq * 8));
#pragma unroll
        for (int j = 0; j < 4; j++)
            bfr[j] = *(const frag_ab*)(sB + ((wx * 64 + j * 16 + m15) * 32 + kq * 8));
#pragma unroll
        for (int i = 0; i < 4; i++)
#pragma unroll
            for (int j = 0; j < 4; j++)
                acc[i][j] = __builtin_amdgcn_mfma_f32_16x16x32_bf16(
                    af[i], bfr[j], acc[i][j], 0, 0, 0);
    }

    // Epilogue: D elem (reg r): row = m-base + kq*4 + r, col = n-base + m15
#pragma unroll
    for (int j = 0; j < 4; j++) {
        int col = rowB0 + wx * 64 + j * 16 + m15;
        if (col >= NW_REAL) continue;
        if (col < 1024) {
            float bd = bdelta[col];
#pragma unroll
            for (int i = 0; i < 4; i++) {
#pragma unroll
                for (int r = 0; r < 4; r++) {
                    int row = rowA0 + wy * 64 + i * 16 + kq * 4 + r;
                    float z = acc[i][j][r] + bd;
                    float sp = (z > 20.f) ? z : log1pf(__expf(z));
                    delta[(size_t)row * 1024 + col] = sp;
                }
            }
        } else if (col < 1040) {
            int c = col - 1024;
#pragma unroll
            for (int i = 0; i < 4; i++)
#pragma unroll
                for (int r = 0; r < 4; r++) {
                    int row = rowA0 + wy * 64 + i * 16 + kq * 4 + r;
                    Bmb[(size_t)row * 16 + c] = acc[i][j][r];
                }
        } else {
            int c = col - 1040;
#pragma unroll
            for (int i = 0; i < 4; i++)
#pragma unroll
                for (int r = 0; r < 4; r++) {
                    int row = rowA0 + wy * 64 + i * 16 + kq * 4 + r;
                    Cmb[(size_t)row * 16 + c] = acc[i][j][r];
                }
        }
    }
}

// ---------- chunked scan ----------
// One wave per (b,d). Lane = ng + 4*c: ng in 0..3 (4 n-states each, n=4*ng+j),
// c in 0..15 (chunk of T=128 timesteps). Pass 1: chunk-local (P=prod a, S)
// from h=0. In-wave Hillis-Steele scan composes chunks (shfl_up, no LDS).
// Pass 2: re-run chunk from true start state, emit y.
#define CHUNKS 16
#define TCH    128   // SEQL / CHUNKS

__global__ __launch_bounds__(256) void scan_kernel(
    const float* __restrict__ delta, const float* __restrict__ Bmb,
    const float* __restrict__ Cmb, const float* __restrict__ x,
    const float* __restrict__ log_A, const float* __restrict__ Dv,
    float* __restrict__ y) {
    const int wave_g = blockIdx.x * 4 + (threadIdx.x >> 6);  // 0..2047
    const int d = wave_g & (DMODEL - 1);
    const int b = wave_g >> 10;
    const int lane = threadIdx.x & 63;
    const int ng = lane & 3;           // n-group: n = 4*ng + j
    const int c  = lane >> 2;          // chunk index 0..15
    const int n0 = ng * 4;

    float4 lA = *(const float4*)(log_A + d * NSTATE + n0);
    float A0 = -__expf(lA.x), A1 = -__expf(lA.y);
    float A2 = -__expf(lA.z), A3 = -__expf(lA.w);
    const float Dd = Dv[d];

    const int t0 = c * TCH;
    const size_t base_x  = ((size_t)b * SEQL + t0) * DMODEL + d;  // +DMODEL per t
    const size_t base_bc = ((size_t)b * SEQL + t0) * NSTATE + n0; // +NSTATE per t

    // ---- pass 1: chunk-local (P, S) from h = 0 ----
    float P0 = 1.f, P1 = 1.f, P2 = 1.f, P3 = 1.f;
    float S0 = 0.f, S1 = 0.f, S2 = 0.f, S3 = 0.f;
    {
        size_t ix = base_x, ib = base_bc;
#pragma unroll 2
        for (int t = 0; t < TCH; ++t) {
            float dl = delta[ix];
            float xl = x[ix];
            float4 bm = *(const float4*)(Bmb + ib);
            float dx = dl * xl;
            float a0 = __expf(dl * A0), a1 = __expf(dl * A1);
            float a2 = __expf(dl * A2), a3 = __expf(dl * A3);
            S0 = fmaf(a0, S0, dx * bm.x); P0 *= a0;
            S1 = fmaf(a1, S1, dx * bm.y); P1 *= a1;
            S2 = fmaf(a2, S2, dx * bm.z); P2 *= a2;
            S3 = fmaf(a3, S3, dx * bm.w); P3 *= a3;
            ix += DMODEL; ib += NSTATE;
        }
    }

    // ---- in-wave inclusive scan over chunks: (P,S)_self ∘ (P,S)_prev ----
#pragma unroll
    for (int off = 1; off < CHUNKS; off <<= 1) {
        int lo = off * 4;
        float p0 = __shfl_up(P0, lo), s0 = __shfl_up(S0, lo);
        float p1 = __shfl_up(P1, lo), s1 = __shfl_up(S1, lo);
        float p2 = __shfl_up(P2, lo), s2 = __shfl_up(S2, lo);
        float p3 = __shfl_up(P3, lo), s3 = __shfl_up(S3, lo);
        if (c >= off) {
            S0 = fmaf(P0, s0, S0); P0 *= p0;
            S1 = fmaf(P1, s1, S1); P1 *= p1;
            S2 = fmaf(P2, s2, S2); P2 *= p2;
            S3 = fmaf(P3, s3, S3); P3 *= p3;
        }
    }
    // exclusive: start state of chunk c = inclusive result of chunk c-1
    float H0 = __shfl_up(S0, 4), H1 = __shfl_up(S1, 4);
    float H2 = __shfl_up(S2, 4), H3 = __shfl_up(S3, 4);
    if (c == 0) { H0 = 0.f; H1 = 0.f; H2 = 0.f; H3 = 0.f; }

    // ---- pass 2: re-run chunk from true start state, emit y ----
    float h0 = H0, h1 = H1, h2 = H2, h3 = H3;
    {
        size_t ix = base_x, ib = base_bc;
#pragma unroll 2
        for (int t = 0; t < TCH; ++t) {
            float dl = delta[ix];
            float xl = x[ix];
            float4 bm = *(const float4*)(Bmb + ib);
            float4 cm = *(const float4*)(Cmb + ib);
            float dx = dl * xl;
            float a0 = __expf(dl * A0), a1 = __expf(dl * A1);
            float a2 = __expf(dl * A2), a3 = __expf(dl * A3);
            h0 = fmaf(a0, h0, dx * bm.x);
            h1 = fmaf(a1, h1, dx * bm.y);
            h2 = fmaf(a2, h2, dx * bm.z);
            h3 = fmaf(a3, h3, dx * bm.w);
            float dot = h0 * cm.x + h1 * cm.y + h2 * cm.z + h3 * cm.w;
            dot += __shfl_xor(dot, 1);
            dot += __shfl_xor(dot, 2);
            if (ng == 0) y[ix] = fmaf(xl, Dd, dot);
            ix += DMODEL; ib += NSTATE;
        }
    }
}

extern "C" void kernel_launch(void* const* d_in, const int* in_sizes, int n_in,
                              void* d_out, int out_size, void* d_ws, size_t ws_size,
                              hipStream_t stream) {
    const float* x      = (const float*)d_in[0];
    const float* Wb     = (const float*)d_in[1];
    const float* Wc     = (const float*)d_in[2];
    const float* Wdelta = (const float*)d_in[3];
    const float* bdelta = (const float*)d_in[4];
    const float* log_A  = (const float*)d_in[5];
    const float* Dv     = (const float*)d_in[6];
    float* y = (float*)d_out;

    char* ws = (char*)d_ws;
    ushort_t* x16 = (ushort_t*)ws;                               // 8,388,608 B
    ushort_t* w16 = (ushort_t*)(ws + 8388608);                   // 2,359,296 B
    float* delta  = (float*)(ws + 8388608 + 2359296);            // 16,777,216 B
    float* Bmb    = (float*)(ws + 8388608 + 2359296 + 16777216); //   262,144 B
    float* Cmb    = (float*)(ws + 8388608 + 2359296 + 16777216 + 262144);

    convert_kernel<<<(XN + WN) / 4 / 256, 256, 0, stream>>>(x, Wdelta, Wb, Wc, x16, w16);
    gemm_kernel<<<dim3(32, 9), 256, 0, stream>>>(x16, w16, bdelta, delta, Bmb, Cmb);
    // one wave per (b,d): 2048 waves, 4 waves/block -> 512 blocks
    scan_kernel<<<(B_SZ * DMODEL) / 4, 256, 0, stream>>>(
        delta, Bmb, Cmb, x, log_A, Dv, y);
}

// Round 4
// 207.583 us; speedup vs baseline: 4.9169x; 1.2806x over previous
//
#include <hip/hip_runtime.h>
#include <cstdint>
#include <cstddef>

#define B_SZ 2
#define SEQL 2048
#define DMODEL 1024
#define NSTATE 16
#define M_TOTAL (B_SZ * SEQL)      // 4096 rows of x
#define NW_REAL 1056               // Wdelta(1024) + Wb(16) + Wc(16)
#define NW_ALL  1152
#define XN (M_TOTAL * DMODEL)      // 4,194,304
#define WN (NW_ALL * DMODEL)       // 1,179,648

typedef unsigned short ushort_t;

// ---------- fp32 -> bf16 (RNE) ----------
__device__ __forceinline__ ushort_t f2bf(float f) {
    unsigned int u = __float_as_uint(f);
    u = (u + 0x7FFFu + ((u >> 16) & 1u)) >> 16;
    return (ushort_t)u;
}
__device__ __forceinline__ float bf2f(ushort_t u) {
    return __uint_as_float(((unsigned int)u) << 16);
}

// ---------- convert x: emit x16 (bf16, (M,K)) + x_t (bf16, (b,d,l)) ----------
// 64x64 LDS-tiled transpose. grid = 64 (M/64) x 16 (D/64) = 1024 blocks.
__global__ __launch_bounds__(256) void convert_x_kernel(
    const float* __restrict__ x, ushort_t* __restrict__ x16,
    ushort_t* __restrict__ x_t) {
    __shared__ float tile[64][65];
    const int mt = blockIdx.x >> 4;
    const int dt = blockIdx.x & 15;
    const int row0 = mt * 64;               // global M row (b*L + l)
    const int d0 = dt * 64;
    const int tid = threadIdx.x;
#pragma unroll
    for (int it = 0; it < 4; ++it) {
        int lin = tid + it * 256;
        int rr = lin >> 4, c4 = lin & 15;
        float4 v = *(const float4*)(x + (size_t)(row0 + rr) * 1024 + d0 + c4 * 4);
        ushort4 o; o.x = f2bf(v.x); o.y = f2bf(v.y); o.z = f2bf(v.z); o.w = f2bf(v.w);
        *(ushort4*)(x16 + (size_t)(row0 + rr) * 1024 + d0 + c4 * 4) = o;
        tile[rr][c4 * 4 + 0] = v.x; tile[rr][c4 * 4 + 1] = v.y;
        tile[rr][c4 * 4 + 2] = v.z; tile[rr][c4 * 4 + 3] = v.w;
    }
    __syncthreads();
    const int b = row0 >> 11;
    const int l0 = row0 & 2047;
#pragma unroll
    for (int it = 0; it < 4; ++it) {
        int lin = tid + it * 256;
        int dd = lin >> 4, l4 = lin & 15;
        ushort4 o;
        o.x = f2bf(tile[l4 * 4 + 0][dd]);
        o.y = f2bf(tile[l4 * 4 + 1][dd]);
        o.z = f2bf(tile[l4 * 4 + 2][dd]);
        o.w = f2bf(tile[l4 * 4 + 3][dd]);
        *(ushort4*)(x_t + ((size_t)b * 1024 + d0 + dd) * 2048 + l0 + l4 * 4) = o;
    }
}

// ---------- convert weights [Wdelta; Wb; Wc; pad] -> w16 (1152x1024 bf16) ----------
__global__ __launch_bounds__(256) void convert_w_kernel(
    const float* __restrict__ Wd, const float* __restrict__ Wb,
    const float* __restrict__ Wc, ushort_t* __restrict__ w16) {
    int j = (blockIdx.x * 256 + threadIdx.x) * 4;
    int row = j >> 10, col = j & 1023;
    float4 v;
    if (row < 1024)      v = *(const float4*)(Wd + row * 1024 + col);
    else if (row < 1040) v = *(const float4*)(Wb + (row - 1024) * 1024 + col);
    else if (row < 1056) v = *(const float4*)(Wc + (row - 1040) * 1024 + col);
    else                 v = make_float4(0.f, 0.f, 0.f, 0.f);
    ushort4 o;
    o.x = f2bf(v.x); o.y = f2bf(v.y); o.z = f2bf(v.z); o.w = f2bf(v.w);
    *(ushort4*)(w16 + j) = o;
}

// ---------- MFMA GEMM: x16 @ w16^T, BM=128 BN=64 BK=32, fused epilogue ----------
typedef __attribute__((ext_vector_type(8))) short frag_ab;
typedef __attribute__((ext_vector_type(4))) float frag_cd;

__device__ __forceinline__ void lds_load16(const ushort_t* g, ushort_t* l) {
    __builtin_amdgcn_global_load_lds(
        (const __attribute__((address_space(1))) unsigned int*)g,
        (__attribute__((address_space(3))) unsigned int*)l, 16, 0, 0);
}

// grid = (32, 17): M tiles x N tiles (cols 0..1087; 1056..1087 padding skipped).
// 4 waves 2x2, wave tile 64x32 via 4x2 MFMAs of 16x16x32.
// delta written TRANSPOSED (b,d,l) fp32; Bmb/Cmb (b,t,n) fp32.
__global__ __launch_bounds__(256) void gemm_kernel(
    const ushort_t* __restrict__ x16, const ushort_t* __restrict__ w16,
    const float* __restrict__ bdelta,
    float* __restrict__ delta_t, float* __restrict__ Bmb, float* __restrict__ Cmb) {
    __shared__ ushort_t sA[128 * 32];
    __shared__ ushort_t sB[64 * 32];
    const int tid = threadIdx.x;
    const int lane = tid & 63;
    const int wv = tid >> 6;
    const int wy = wv >> 1, wx = wv & 1;
    const int m15 = lane & 15, kq = lane >> 4;
    const int rowA0 = blockIdx.x * 128;
    const int rowB0 = blockIdx.y * 64;

    frag_cd acc[4][2];
#pragma unroll
    for (int i = 0; i < 4; i++)
#pragma unroll
        for (int j = 0; j < 2; j++)
            acc[i][j] = (frag_cd){0.f, 0.f, 0.f, 0.f};

    const int c0 = tid, c1 = tid + 256;
    const int rA0 = c0 >> 2, cA0 = (c0 & 3) * 8;
    const int rA1 = c1 >> 2, cA1 = (c1 & 3) * 8;

    for (int k0 = 0; k0 < 1024; k0 += 32) {
        __syncthreads();
        lds_load16(x16 + (size_t)(rowA0 + rA0) * 1024 + k0 + cA0, sA + c0 * 8);
        lds_load16(x16 + (size_t)(rowA0 + rA1) * 1024 + k0 + cA1, sA + c1 * 8);
        lds_load16(w16 + (size_t)(rowB0 + rA0) * 1024 + k0 + cA0, sB + c0 * 8);
        __syncthreads();

        frag_ab af[4], bfr[2];
#pragma unroll
        for (int i = 0; i < 4; i++)
            af[i] = *(const frag_ab*)(sA + ((wy * 64 + i * 16 + m15) * 32 + kq * 8));
#pragma unroll
        for (int j = 0; j < 2; j++)
            bfr[j] = *(const frag_ab*)(sB + ((wx * 32 + j * 16 + m15) * 32 + kq * 8));
#pragma unroll
        for (int i = 0; i < 4; i++)
#pragma unroll
            for (int j = 0; j < 2; j++)
                acc[i][j] = __builtin_amdgcn_mfma_f32_16x16x32_bf16(
                    af[i], bfr[j], acc[i][j], 0, 0, 0);
    }

    // C/D layout: reg r -> row = base + kq*4 + r (4 consecutive M rows), col = base + m15.
#pragma unroll
    for (int j = 0; j < 2; j++) {
        int col = rowB0 + wx * 32 + j * 16 + m15;
        if (col >= NW_REAL) continue;
        if (col < 1024) {
            float bd = bdelta[col];
#pragma unroll
            for (int i = 0; i < 4; i++) {
                int row = rowA0 + wy * 64 + i * 16 + kq * 4;   // 4 consecutive l
                int b = row >> 11, l = row & 2047;
                float4 o;
                float z0 = acc[i][j][0] + bd, z1 = acc[i][j][1] + bd;
                float z2 = acc[i][j][2] + bd, z3 = acc[i][j][3] + bd;
                o.x = (z0 > 20.f) ? z0 : log1pf(__expf(z0));
                o.y = (z1 > 20.f) ? z1 : log1pf(__expf(z1));
                o.z = (z2 > 20.f) ? z2 : log1pf(__expf(z2));
                o.w = (z3 > 20.f) ? z3 : log1pf(__expf(z3));
                *(float4*)(delta_t + ((size_t)b * 1024 + col) * 2048 + l) = o;
            }
        } else if (col < 1040) {
            int c = col - 1024;
#pragma unroll
            for (int i = 0; i < 4; i++)
#pragma unroll
                for (int r = 0; r < 4; r++) {
                    int row = rowA0 + wy * 64 + i * 16 + kq * 4 + r;
                    Bmb[(size_t)row * 16 + c] = acc[i][j][r];
                }
        } else {
            int c = col - 1040;
#pragma unroll
            for (int i = 0; i < 4; i++)
#pragma unroll
                for (int r = 0; r < 4; r++) {
                    int row = rowA0 + wy * 64 + i * 16 + kq * 4 + r;
                    Cmb[(size_t)row * 16 + c] = acc[i][j][r];
                }
        }
    }
}

// ---------- chunked scan, block = one (b,d) ----------
// 256 threads: ng = tid&3 (4 n each), cc = tid>>2 (64 chunks of 32 t).
// Hierarchical prefix: in-wave shfl scan over 16 chunks, LDS combine across 4 waves.
__global__ __launch_bounds__(256) void scan_kernel(
    const float* __restrict__ delta_t, const ushort_t* __restrict__ x_t,
    const float* __restrict__ Bmb, const float* __restrict__ Cmb,
    const float* __restrict__ log_A, const float* __restrict__ Dv,
    ushort_t* __restrict__ y_t) {
    __shared__ float sP[64], sS[64];
    const int bd = blockIdx.x;               // 0..2047
    const int d = bd & 1023, b = bd >> 10;
    const int tid = threadIdx.x;
    const int ng = tid & 3, cc = tid >> 2, w = tid >> 6, cw = cc & 15;
    const int n0 = ng * 4;

    float4 lA = *(const float4*)(log_A + d * NSTATE + n0);
    const float A0 = -__expf(lA.x), A1 = -__expf(lA.y);
    const float A2 = -__expf(lA.z), A3 = -__expf(lA.w);
    const float Dd = Dv[d];

    const int t0 = cc * 32;
    const size_t base_dx = ((size_t)b * 1024 + d) * 2048 + t0;   // +1 per t
    const size_t base_bc = ((size_t)b * 2048 + t0) * 16 + n0;    // +16 per t

    // ---- pass 1: chunk-local (P, S) from h = 0 ----
    float P0 = 1.f, P1 = 1.f, P2 = 1.f, P3 = 1.f;
    float S0 = 0.f, S1 = 0.f, S2 = 0.f, S3 = 0.f;
#pragma unroll 4
    for (int t = 0; t < 32; ++t) {
        float dl = delta_t[base_dx + t];
        float xl = bf2f(x_t[base_dx + t]);
        float4 bm = *(const float4*)(Bmb + base_bc + t * 16);
        float dx = dl * xl;
        float a0 = __expf(dl * A0), a1 = __expf(dl * A1);
        float a2 = __expf(dl * A2), a3 = __expf(dl * A3);
        S0 = fmaf(a0, S0, dx * bm.x); P0 *= a0;
        S1 = fmaf(a1, S1, dx * bm.y); P1 *= a1;
        S2 = fmaf(a2, S2, dx * bm.z); P2 *= a2;
        S3 = fmaf(a3, S3, dx * bm.w); P3 *= a3;
    }

    // ---- in-wave inclusive scan over cw ----
#pragma unroll
    for (int off = 1; off < 16; off <<= 1) {
        int lo = off * 4;
        float p0 = __shfl_up(P0, lo), s0 = __shfl_up(S0, lo);
        float p1 = __shfl_up(P1, lo), s1 = __shfl_up(S1, lo);
        float p2 = __shfl_up(P2, lo), s2 = __shfl_up(S2, lo);
        float p3 = __shfl_up(P3, lo), s3 = __shfl_up(S3, lo);
        if (cw >= off) {
            S0 = fmaf(P0, s0, S0); P0 *= p0;
            S1 = fmaf(P1, s1, S1); P1 *= p1;
            S2 = fmaf(P2, s2, S2); P2 *= p2;
            S3 = fmaf(P3, s3, S3); P3 *= p3;
        }
    }
    // wave aggregate (cw==15 inclusive) -> LDS
    if (cw == 15) {
        sP[w * 16 + n0 + 0] = P0; sS[w * 16 + n0 + 0] = S0;
        sP[w * 16 + n0 + 1] = P1; sS[w * 16 + n0 + 1] = S1;
        sP[w * 16 + n0 + 2] = P2; sS[w * 16 + n0 + 2] = S2;
        sP[w * 16 + n0 + 3] = P3; sS[w * 16 + n0 + 3] = S3;
    }
    __syncthreads();
    // state entering this wave = compose of waves 0..w-1 applied to 0
    float H0 = 0.f, H1 = 0.f, H2 = 0.f, H3 = 0.f;
    for (int q = 0; q < w; ++q) {
        H0 = fmaf(sP[q * 16 + n0 + 0], H0, sS[q * 16 + n0 + 0]);
        H1 = fmaf(sP[q * 16 + n0 + 1], H1, sS[q * 16 + n0 + 1]);
        H2 = fmaf(sP[q * 16 + n0 + 2], H2, sS[q * 16 + n0 + 2]);
        H3 = fmaf(sP[q * 16 + n0 + 3], H3, sS[q * 16 + n0 + 3]);
    }
    // exclusive within wave: op of chunks [w*16, cc) from shfl_up of inclusive
    float Pe0 = __shfl_up(P0, 4), Se0 = __shfl_up(S0, 4);
    float Pe1 = __shfl_up(P1, 4), Se1 = __shfl_up(S1, 4);
    float Pe2 = __shfl_up(P2, 4), Se2 = __shfl_up(S2, 4);
    float Pe3 = __shfl_up(P3, 4), Se3 = __shfl_up(S3, 4);
    float h0, h1, h2, h3;
    if (cw == 0) { h0 = H0; h1 = H1; h2 = H2; h3 = H3; }
    else {
        h0 = fmaf(Pe0, H0, Se0); h1 = fmaf(Pe1, H1, Se1);
        h2 = fmaf(Pe2, H2, Se2); h3 = fmaf(Pe3, H3, Se3);
    }

    // ---- pass 2: run chunk from true start state, emit y_t ----
#pragma unroll 4
    for (int t = 0; t < 32; ++t) {
        float dl = delta_t[base_dx + t];
        float xl = bf2f(x_t[base_dx + t]);
        float4 bm = *(const float4*)(Bmb + base_bc + t * 16);
        float4 cm = *(const float4*)(Cmb + base_bc + t * 16);
        float dx = dl * xl;
        float a0 = __expf(dl * A0), a1 = __expf(dl * A1);
        float a2 = __expf(dl * A2), a3 = __expf(dl * A3);
        h0 = fmaf(a0, h0, dx * bm.x);
        h1 = fmaf(a1, h1, dx * bm.y);
        h2 = fmaf(a2, h2, dx * bm.z);
        h3 = fmaf(a3, h3, dx * bm.w);
        float dot = h0 * cm.x + h1 * cm.y + h2 * cm.z + h3 * cm.w;
        dot += __shfl_xor(dot, 1);
        dot += __shfl_xor(dot, 2);
        if (ng == 0) y_t[base_dx + t] = f2bf(fmaf(xl, Dd, dot));
    }
}

// ---------- finalize: y_t bf16 (b,d,l) -> y fp32 (b,l,d), tiled transpose ----------
// grid = 2 (b) * 32 (L/64) * 16 (D/64) = 1024 blocks.
__global__ __launch_bounds__(256) void finalize_kernel(
    const ushort_t* __restrict__ y_t, float* __restrict__ y) {
    __shared__ float tile[64][65];   // [d][l]
    const int bt = blockIdx.x;
    const int b = bt >> 9;
    const int rem = bt & 511;
    const int l0 = (rem >> 4) * 64;
    const int d0 = (rem & 15) * 64;
    const int tid = threadIdx.x;
#pragma unroll
    for (int it = 0; it < 4; ++it) {
        int lin = tid + it * 256;
        int dd = lin >> 4, l4 = lin & 15;
        ushort4 v = *(const ushort4*)(y_t + ((size_t)b * 1024 + d0 + dd) * 2048 + l0 + l4 * 4);
        tile[dd][l4 * 4 + 0] = bf2f(v.x);
        tile[dd][l4 * 4 + 1] = bf2f(v.y);
        tile[dd][l4 * 4 + 2] = bf2f(v.z);
        tile[dd][l4 * 4 + 3] = bf2f(v.w);
    }
    __syncthreads();
#pragma unroll
    for (int it = 0; it < 4; ++it) {
        int lin = tid + it * 256;
        int ll = lin >> 4, d4 = lin & 15;
        float4 o;
        o.x = tile[d4 * 4 + 0][ll];
        o.y = tile[d4 * 4 + 1][ll];
        o.z = tile[d4 * 4 + 2][ll];
        o.w = tile[d4 * 4 + 3][ll];
        *(float4*)(y + ((size_t)b * 2048 + l0 + ll) * 1024 + d0 + d4 * 4) = o;
    }
}

extern "C" void kernel_launch(void* const* d_in, const int* in_sizes, int n_in,
                              void* d_out, int out_size, void* d_ws, size_t ws_size,
                              hipStream_t stream) {
    const float* x      = (const float*)d_in[0];
    const float* Wb     = (const float*)d_in[1];
    const float* Wc     = (const float*)d_in[2];
    const float* Wdelta = (const float*)d_in[3];
    const float* bdelta = (const float*)d_in[4];
    const float* log_A  = (const float*)d_in[5];
    const float* Dv     = (const float*)d_in[6];
    float* y = (float*)d_out;

    char* ws = (char*)d_ws;
    ushort_t* x16    = (ushort_t*)ws;                     //  8,388,608 B
    ushort_t* w16    = (ushort_t*)(ws + 8388608);         //  2,359,296 B
    ushort_t* x_t    = (ushort_t*)(ws + 10747904);        //  8,388,608 B
    float*    delta_t= (float*)(ws + 19136512);           // 16,777,216 B
    float*    Bmb    = (float*)(ws + 35913728);           //    262,144 B
    float*    Cmb    = (float*)(ws + 36175872);           //    262,144 B  (end 36.4 MB)
    // y_t (bf16, 8,388,608 B) aliases x16: x16 is dead after gemm, y_t written by scan.
    ushort_t* y_t    = (ushort_t*)ws;

    convert_x_kernel<<<1024, 256, 0, stream>>>(x, x16, x_t);
    convert_w_kernel<<<WN / 4 / 256, 256, 0, stream>>>(Wdelta, Wb, Wc, w16);
    gemm_kernel<<<dim3(32, 17), 256, 0, stream>>>(x16, w16, bdelta, delta_t, Bmb, Cmb);
    scan_kernel<<<B_SZ * DMODEL, 256, 0, stream>>>(delta_t, x_t, Bmb, Cmb, log_A, Dv, y_t);
    finalize_kernel<<<1024, 256, 0, stream>>>(y_t, y);
}

// Round 5
// 175.692 us; speedup vs baseline: 5.8094x; 1.1815x over previous
//
#include <hip/hip_runtime.h>
#include <cstdint>
#include <cstddef>

#define B_SZ 2
#define SEQL 2048
#define DMODEL 1024
#define NSTATE 16
#define M_TOTAL (B_SZ * SEQL)
#define NW_REAL 1056               // Wdelta(1024) + Wb(16) + Wc(16)
#define NW_ALL  1152
#define XN (M_TOTAL * DMODEL)      // 4,194,304
#define WN (NW_ALL * DMODEL)       // 1,179,648

typedef unsigned short ushort_t;

// ---------- fp32 -> bf16 (RNE) ----------
__device__ __forceinline__ ushort_t f2bf(float f) {
    unsigned int u = __float_as_uint(f);
    u = (u + 0x7FFFu + ((u >> 16) & 1u)) >> 16;
    return (ushort_t)u;
}
__device__ __forceinline__ float bf2f(ushort_t u) {
    return __uint_as_float(((unsigned int)u) << 16);
}

// ---------- fused convert: x -> x16 (M,K) + x_t (b,d,l); W -> w16 ----------
// blocks 0..1023: x tiles (64x64 LDS transpose). blocks 1024..2175: weights.
__global__ __launch_bounds__(256) void convert_kernel(
    const float* __restrict__ x, const float* __restrict__ Wd,
    const float* __restrict__ Wb, const float* __restrict__ Wc,
    ushort_t* __restrict__ x16, ushort_t* __restrict__ x_t,
    ushort_t* __restrict__ w16) {
    __shared__ float tile[64][65];
    const int tid = threadIdx.x;
    if (blockIdx.x >= 1024) {
        int j = ((blockIdx.x - 1024) * 256 + tid) * 4;
        int row = j >> 10, col = j & 1023;
        float4 v;
        if (row < 1024)      v = *(const float4*)(Wd + row * 1024 + col);
        else if (row < 1040) v = *(const float4*)(Wb + (row - 1024) * 1024 + col);
        else if (row < 1056) v = *(const float4*)(Wc + (row - 1040) * 1024 + col);
        else                 v = make_float4(0.f, 0.f, 0.f, 0.f);
        ushort4 o;
        o.x = f2bf(v.x); o.y = f2bf(v.y); o.z = f2bf(v.z); o.w = f2bf(v.w);
        *(ushort4*)(w16 + j) = o;
        return;
    }
    const int mt = blockIdx.x >> 4;
    const int dt = blockIdx.x & 15;
    const int row0 = mt * 64;
    const int d0 = dt * 64;
#pragma unroll
    for (int it = 0; it < 4; ++it) {
        int lin = tid + it * 256;
        int rr = lin >> 4, c4 = lin & 15;
        float4 v = *(const float4*)(x + (size_t)(row0 + rr) * 1024 + d0 + c4 * 4);
        ushort4 o; o.x = f2bf(v.x); o.y = f2bf(v.y); o.z = f2bf(v.z); o.w = f2bf(v.w);
        *(ushort4*)(x16 + (size_t)(row0 + rr) * 1024 + d0 + c4 * 4) = o;
        tile[rr][c4 * 4 + 0] = v.x; tile[rr][c4 * 4 + 1] = v.y;
        tile[rr][c4 * 4 + 2] = v.z; tile[rr][c4 * 4 + 3] = v.w;
    }
    __syncthreads();
    const int b = row0 >> 11;
    const int l0 = row0 & 2047;
#pragma unroll
    for (int it = 0; it < 4; ++it) {
        int lin = tid + it * 256;
        int dd = lin >> 4, l4 = lin & 15;
        ushort4 o;
        o.x = f2bf(tile[l4 * 4 + 0][dd]);
        o.y = f2bf(tile[l4 * 4 + 1][dd]);
        o.z = f2bf(tile[l4 * 4 + 2][dd]);
        o.w = f2bf(tile[l4 * 4 + 3][dd]);
        *(ushort4*)(x_t + ((size_t)b * 1024 + d0 + dd) * 2048 + l0 + l4 * 4) = o;
    }
}

// ---------- MFMA GEMM: x16 @ w16^T, BM=128 BN=64 BK=32, fused epilogue ----------
typedef __attribute__((ext_vector_type(8))) short frag_ab;
typedef __attribute__((ext_vector_type(4))) float frag_cd;

__device__ __forceinline__ void lds_load16(const ushort_t* g, ushort_t* l) {
    __builtin_amdgcn_global_load_lds(
        (const __attribute__((address_space(1))) unsigned int*)g,
        (__attribute__((address_space(3))) unsigned int*)l, 16, 0, 0);
}

__global__ __launch_bounds__(256) void gemm_kernel(
    const ushort_t* __restrict__ x16, const ushort_t* __restrict__ w16,
    const float* __restrict__ bdelta,
    float* __restrict__ delta_t, float* __restrict__ Bmb, float* __restrict__ Cmb) {
    __shared__ ushort_t sA[128 * 32];
    __shared__ ushort_t sB[64 * 32];
    const int tid = threadIdx.x;
    const int lane = tid & 63;
    const int wv = tid >> 6;
    const int wy = wv >> 1, wx = wv & 1;
    const int m15 = lane & 15, kq = lane >> 4;
    const int rowA0 = blockIdx.x * 128;
    const int rowB0 = blockIdx.y * 64;

    frag_cd acc[4][2];
#pragma unroll
    for (int i = 0; i < 4; i++)
#pragma unroll
        for (int j = 0; j < 2; j++)
            acc[i][j] = (frag_cd){0.f, 0.f, 0.f, 0.f};

    const int c0 = tid, c1 = tid + 256;
    const int rA0 = c0 >> 2, cA0 = (c0 & 3) * 8;
    const int rA1 = c1 >> 2, cA1 = (c1 & 3) * 8;

    for (int k0 = 0; k0 < 1024; k0 += 32) {
        __syncthreads();
        lds_load16(x16 + (size_t)(rowA0 + rA0) * 1024 + k0 + cA0, sA + c0 * 8);
        lds_load16(x16 + (size_t)(rowA0 + rA1) * 1024 + k0 + cA1, sA + c1 * 8);
        lds_load16(w16 + (size_t)(rowB0 + rA0) * 1024 + k0 + cA0, sB + c0 * 8);
        __syncthreads();

        frag_ab af[4], bfr[2];
#pragma unroll
        for (int i = 0; i < 4; i++)
            af[i] = *(const frag_ab*)(sA + ((wy * 64 + i * 16 + m15) * 32 + kq * 8));
#pragma unroll
        for (int j = 0; j < 2; j++)
            bfr[j] = *(const frag_ab*)(sB + ((wx * 32 + j * 16 + m15) * 32 + kq * 8));
#pragma unroll
        for (int i = 0; i < 4; i++)
#pragma unroll
            for (int j = 0; j < 2; j++)
                acc[i][j] = __builtin_amdgcn_mfma_f32_16x16x32_bf16(
                    af[i], bfr[j], acc[i][j], 0, 0, 0);
    }

#pragma unroll
    for (int j = 0; j < 2; j++) {
        int col = rowB0 + wx * 32 + j * 16 + m15;
        if (col >= NW_REAL) continue;
        if (col < 1024) {
            float bd = bdelta[col];
#pragma unroll
            for (int i = 0; i < 4; i++) {
                int row = rowA0 + wy * 64 + i * 16 + kq * 4;
                int b = row >> 11, l = row & 2047;
                float4 o;
                float z0 = acc[i][j][0] + bd, z1 = acc[i][j][1] + bd;
                float z2 = acc[i][j][2] + bd, z3 = acc[i][j][3] + bd;
                o.x = (z0 > 20.f) ? z0 : log1pf(__expf(z0));
                o.y = (z1 > 20.f) ? z1 : log1pf(__expf(z1));
                o.z = (z2 > 20.f) ? z2 : log1pf(__expf(z2));
                o.w = (z3 > 20.f) ? z3 : log1pf(__expf(z3));
                *(float4*)(delta_t + ((size_t)b * 1024 + col) * 2048 + l) = o;
            }
        } else if (col < 1040) {
            int c = col - 1024;
#pragma unroll
            for (int i = 0; i < 4; i++)
#pragma unroll
                for (int r = 0; r < 4; r++) {
                    int row = rowA0 + wy * 64 + i * 16 + kq * 4 + r;
                    Bmb[(size_t)row * 16 + c] = acc[i][j][r];
                }
        } else {
            int c = col - 1040;
#pragma unroll
            for (int i = 0; i < 4; i++)
#pragma unroll
                for (int r = 0; r < 4; r++) {
                    int row = rowA0 + wy * 64 + i * 16 + kq * 4 + r;
                    Cmb[(size_t)row * 16 + c] = acc[i][j][r];
                }
        }
    }
}

// ---------- chunked scan: block = (b, d-pair), all 16 n in-thread ----------
// 256 threads: dg = tid&1 (2 d), cc = tid>>1 (128 chunks of 16 t).
// Pass 1: chunk-local (P[16], S[16]). In-wave shfl scan over 32 chunks/wave,
// LDS combine across 4 waves. Pass 2: replay from true state, in-register
// 16-fma dot, bf16 y_t stores (no shuffles in hot loops).
__global__ __launch_bounds__(256) void scan_kernel(
    const float* __restrict__ delta_t, const ushort_t* __restrict__ x_t,
    const float* __restrict__ Bmb, const float* __restrict__ Cmb,
    const float* __restrict__ log_A, const float* __restrict__ Dv,
    ushort_t* __restrict__ y_t) {
    __shared__ float sP[128], sS[128];   // [w][dg][n]
    const int bd = blockIdx.x;           // 0..1023
    const int d0 = (bd & 511) * 2, b = bd >> 9;
    const int tid = threadIdx.x;
    const int dg = tid & 1, cc = tid >> 1;         // cc 0..127
    const int w = tid >> 6, cw = (tid & 63) >> 1;  // cw 0..31
    const int d = d0 + dg;

    float A[16];
    {
        const float4* lap = (const float4*)(log_A + d * NSTATE);
#pragma unroll
        for (int q = 0; q < 4; ++q) {
            float4 la = lap[q];
            A[q * 4 + 0] = -__expf(la.x);
            A[q * 4 + 1] = -__expf(la.y);
            A[q * 4 + 2] = -__expf(la.z);
            A[q * 4 + 3] = -__expf(la.w);
        }
    }
    const float Dd = Dv[d];
    const int t0 = cc * 16;
    const size_t base_dx = ((size_t)b * 1024 + d) * 2048 + t0;   // +1 per t
    const size_t base_bc = ((size_t)b * 2048 + t0) * 16;         // +16 per t

    float S[16], P[16];
#pragma unroll
    for (int n = 0; n < 16; ++n) { S[n] = 0.f; P[n] = 1.f; }

    // ---- pass 1 ----
#pragma unroll
    for (int tq = 0; tq < 4; ++tq) {
        float4 dl4 = *(const float4*)(delta_t + base_dx + tq * 4);
        ushort4 xl4 = *(const ushort4*)(x_t + base_dx + tq * 4);
        const float* dlp = &dl4.x;
        const ushort_t* xlp = &xl4.x;
#pragma unroll
        for (int j = 0; j < 4; ++j) {
            int t = tq * 4 + j;
            float dl = dlp[j];
            float dx = dl * bf2f(xlp[j]);
            const float4* bmp = (const float4*)(Bmb + base_bc + (size_t)t * 16);
            float bm[16];
            *(float4*)(bm + 0) = bmp[0]; *(float4*)(bm + 4) = bmp[1];
            *(float4*)(bm + 8) = bmp[2]; *(float4*)(bm + 12) = bmp[3];
#pragma unroll
            for (int n = 0; n < 16; ++n) {
                float a = __expf(dl * A[n]);
                S[n] = fmaf(a, S[n], dx * bm[n]);
                P[n] *= a;
            }
        }
    }

    // ---- in-wave inclusive scan over cw (32 chunks/wave) ----
#pragma unroll
    for (int off = 1; off < 32; off <<= 1) {
        int lo = off * 2;
        float pp[16], ss[16];
#pragma unroll
        for (int n = 0; n < 16; ++n) {
            pp[n] = __shfl_up(P[n], lo);
            ss[n] = __shfl_up(S[n], lo);
        }
        if (cw >= off) {
#pragma unroll
            for (int n = 0; n < 16; ++n) {
                S[n] = fmaf(P[n], ss[n], S[n]);
                P[n] *= pp[n];
            }
        }
    }
    // ---- cross-wave combine via LDS ----
    if (cw == 31) {
#pragma unroll
        for (int n = 0; n < 16; ++n) {
            sP[(w * 2 + dg) * 16 + n] = P[n];
            sS[(w * 2 + dg) * 16 + n] = S[n];
        }
    }
    __syncthreads();
    float H[16];
#pragma unroll
    for (int n = 0; n < 16; ++n) H[n] = 0.f;
    for (int q = 0; q < w; ++q)
#pragma unroll
        for (int n = 0; n < 16; ++n)
            H[n] = fmaf(sP[(q * 2 + dg) * 16 + n], H[n], sS[(q * 2 + dg) * 16 + n]);

    // exclusive state entering this chunk
    float h[16];
#pragma unroll
    for (int n = 0; n < 16; ++n) {
        float Pe = __shfl_up(P[n], 2);
        float Se = __shfl_up(S[n], 2);
        h[n] = (cw == 0) ? H[n] : fmaf(Pe, H[n], Se);
    }

    // ---- pass 2 ----
#pragma unroll
    for (int tq = 0; tq < 4; ++tq) {
        float4 dl4 = *(const float4*)(delta_t + base_dx + tq * 4);
        ushort4 xl4 = *(const ushort4*)(x_t + base_dx + tq * 4);
        const float* dlp = &dl4.x;
        const ushort_t* xlp = &xl4.x;
        ushort4 ys;
        ushort_t* ysp = &ys.x;
#pragma unroll
        for (int j = 0; j < 4; ++j) {
            int t = tq * 4 + j;
            float dl = dlp[j];
            float xl = bf2f(xlp[j]);
            float dx = dl * xl;
            const float4* bmp = (const float4*)(Bmb + base_bc + (size_t)t * 16);
            const float4* cmp = (const float4*)(Cmb + base_bc + (size_t)t * 16);
            float bm[16], cm[16];
            *(float4*)(bm + 0) = bmp[0]; *(float4*)(bm + 4) = bmp[1];
            *(float4*)(bm + 8) = bmp[2]; *(float4*)(bm + 12) = bmp[3];
            *(float4*)(cm + 0) = cmp[0]; *(float4*)(cm + 4) = cmp[1];
            *(float4*)(cm + 8) = cmp[2]; *(float4*)(cm + 12) = cmp[3];
            float dot = 0.f;
#pragma unroll
            for (int n = 0; n < 16; ++n) {
                float a = __expf(dl * A[n]);
                h[n] = fmaf(a, h[n], dx * bm[n]);
                dot = fmaf(h[n], cm[n], dot);
            }
            ysp[j] = f2bf(fmaf(xl, Dd, dot));
        }
        *(ushort4*)(y_t + base_dx + tq * 4) = ys;
    }
}

// ---------- finalize: y_t bf16 (b,d,l) -> y fp32 (b,l,d) ----------
__global__ __launch_bounds__(256) void finalize_kernel(
    const ushort_t* __restrict__ y_t, float* __restrict__ y) {
    __shared__ float tile[64][65];
    const int bt = blockIdx.x;
    const int b = bt >> 9;
    const int rem = bt & 511;
    const int l0 = (rem >> 4) * 64;
    const int d0 = (rem & 15) * 64;
    const int tid = threadIdx.x;
#pragma unroll
    for (int it = 0; it < 4; ++it) {
        int lin = tid + it * 256;
        int dd = lin >> 4, l4 = lin & 15;
        ushort4 v = *(const ushort4*)(y_t + ((size_t)b * 1024 + d0 + dd) * 2048 + l0 + l4 * 4);
        tile[dd][l4 * 4 + 0] = bf2f(v.x);
        tile[dd][l4 * 4 + 1] = bf2f(v.y);
        tile[dd][l4 * 4 + 2] = bf2f(v.z);
        tile[dd][l4 * 4 + 3] = bf2f(v.w);
    }
    __syncthreads();
#pragma unroll
    for (int it = 0; it < 4; ++it) {
        int lin = tid + it * 256;
        int ll = lin >> 4, d4 = lin & 15;
        float4 o;
        o.x = tile[d4 * 4 + 0][ll];
        o.y = tile[d4 * 4 + 1][ll];
        o.z = tile[d4 * 4 + 2][ll];
        o.w = tile[d4 * 4 + 3][ll];
        *(float4*)(y + ((size_t)b * 2048 + l0 + ll) * 1024 + d0 + d4 * 4) = o;
    }
}

extern "C" void kernel_launch(void* const* d_in, const int* in_sizes, int n_in,
                              void* d_out, int out_size, void* d_ws, size_t ws_size,
                              hipStream_t stream) {
    const float* x      = (const float*)d_in[0];
    const float* Wb     = (const float*)d_in[1];
    const float* Wc     = (const float*)d_in[2];
    const float* Wdelta = (const float*)d_in[3];
    const float* bdelta = (const float*)d_in[4];
    const float* log_A  = (const float*)d_in[5];
    const float* Dv     = (const float*)d_in[6];
    float* y = (float*)d_out;

    char* ws = (char*)d_ws;
    ushort_t* x16    = (ushort_t*)ws;                     //  8,388,608 B
    ushort_t* w16    = (ushort_t*)(ws + 8388608);         //  2,359,296 B
    ushort_t* x_t    = (ushort_t*)(ws + 10747904);        //  8,388,608 B
    float*    delta_t= (float*)(ws + 19136512);           // 16,777,216 B
    float*    Bmb    = (float*)(ws + 35913728);           //    262,144 B
    float*    Cmb    = (float*)(ws + 36175872);           //    262,144 B
    // y_t aliases x16 (dead after gemm)
    ushort_t* y_t    = (ushort_t*)ws;

    convert_kernel<<<1024 + WN / 4 / 256, 256, 0, stream>>>(x, Wdelta, Wb, Wc, x16, x_t, w16);
    gemm_kernel<<<dim3(32, 17), 256, 0, stream>>>(x16, w16, bdelta, delta_t, Bmb, Cmb);
    scan_kernel<<<1024, 256, 0, stream>>>(delta_t, x_t, Bmb, Cmb, log_A, Dv, y_t);
    finalize_kernel<<<1024, 256, 0, stream>>>(y_t, y);
}